// Round 1
// baseline (277.990 us; speedup 1.0000x reference)
//
#include <hip/hip_runtime.h>
#include <hip/hip_bf16.h>

// MultiAgentSEPSNetwork: A=8 agents, E=4096, O=256, H1=H2=1024, H3=512, S=4.
// M = A*E = 32768 rows. Only the seps_idx-selected net per agent is computed.
//
// R9: rewrite gemm_mlp from the 2-barrier/K-step 128x128 structure (R8,
// ~781 TF on L2, MfmaUtil 34%) to the 256x256 deep-pipelined phase schedule
// (T2+T3+T4+T5, cf. the verified 8-phase template at 1563-1728 TF):
//  - BK=32, 8 waves (512 thr), per-wave 128x64 C, 16-MFMA cluster per phase.
//  - 4-slot LDS ring (4 x 32KB, dynamic LDS 128KB): stage tile T+2 while
//    computing tile T into the slot dead since tile T-2 -> counted
//    s_waitcnt vmcnt(4) once per K-tile (never 0 in the loop), loads span
//    ~2 tile-periods in flight; architecturally race-free overwrite protocol.
//  - per phase: {ds_read subtile || 2x global_load_lds || barrier ->
//    lgkmcnt(0)+sched_barrier(0) -> setprio(1) 16 MFMA setprio(0) -> barrier}.
// Kept from R5-R8: chunk^row XOR LDS swizzle (0 conflicts), pre-swizzled
// global source for global_load_lds, XCD-swizzled grid (all n-blocks of an
// m-stripe dispatch-adjacent on one XCD; A-stripe L2 reuse), fused prep,
// coalesced LDS-transpose epilogue.

typedef unsigned short u16;
typedef __bf16 bf16x8 __attribute__((ext_vector_type(8)));
typedef float floatx4 __attribute__((ext_vector_type(4)));
typedef unsigned short ushort8 __attribute__((ext_vector_type(8)));

__device__ __forceinline__ u16 f2bf(float f) {
    union { float f; unsigned int u; } v; v.f = f;
    unsigned int u = v.u;
    return (u16)((u + 0x7FFFu + ((u >> 16) & 1u)) >> 16);
}

// global -> LDS direct DMA, 16 B/lane. LDS dest = wave-uniform base + lane*16.
__device__ __forceinline__ void load16(const void* g, void* l) {
    __builtin_amdgcn_global_load_lds(
        (const __attribute__((address_space(1))) void*)(unsigned long long)g,
        (__attribute__((address_space(3))) void*)(unsigned int)(unsigned long long)l,
        16, 0, 0);
}

// ---------------- fused prep: x->bf16 + 3 weight transposes ----------------
__global__ __launch_bounds__(256) void prep(
    const float* __restrict__ x, u16* __restrict__ xb,
    const float* __restrict__ W1, u16* __restrict__ w1t,
    const float* __restrict__ W2, u16* __restrict__ w2t,
    const float* __restrict__ W3, u16* __restrict__ w3t) {
    __shared__ float tile[32][33];
    int b = blockIdx.x;
    const int tid = threadIdx.x;
    if (b < 8192) {
        int i = (b * 256 + tid) * 4;
        float4 v = *(const float4*)(x + i);
        ushort4 o;
        o.x = f2bf(v.x); o.y = f2bf(v.y); o.z = f2bf(v.z); o.w = f2bf(v.w);
        *(ushort4*)(xb + i) = o;
        return;
    }
    b -= 8192;
    const float* src; u16* dst; int K, N, n0, k0, s;
    if (b < 1024) {                     // W1 [4][256][1024] -> [4][1024][256]
        s = b >> 8; int r = b & 255;
        K = 256; N = 1024; n0 = (r & 31) * 32; k0 = (r >> 5) * 32;
        src = W1; dst = w1t;
    } else if (b < 5120) {              // W2 [4][1024][1024] -> same^T
        b -= 1024; s = b >> 10; int r = b & 1023;
        K = 1024; N = 1024; n0 = (r & 31) * 32; k0 = (r >> 5) * 32;
        src = W2; dst = w2t;
    } else {                            // W3 [4][1024][512] -> [4][512][1024]
        b -= 5120; s = b >> 9; int r = b & 511;
        K = 1024; N = 512; n0 = (r & 15) * 32; k0 = (r >> 4) * 32;
        src = W3; dst = w3t;
    }
    src += (size_t)s * K * N;
    dst += (size_t)s * N * K;
    const int tx = tid & 31, ty = tid >> 5;
#pragma unroll
    for (int j = 0; j < 32; j += 8)
        tile[ty + j][tx] = src[(size_t)(k0 + ty + j) * N + (n0 + tx)];
    __syncthreads();
#pragma unroll
    for (int j = 0; j < 32; j += 8)
        dst[(size_t)(n0 + ty + j) * K + (k0 + tx)] = f2bf(tile[tx][ty + j]);
}

// ------------- grouped GEMM: 256x256, BK=32, 4-slot ring, counted vmcnt -------------
// C[m,n] = act(A[M,K] @ Wt[s][N,K]^T + bias[s][N]);  s = seps[agent(m)]
// 512 thr = 8 waves (2x4); per-wave C = 128x64; 16x16x32 MFMA.
// LDS ring: slot (tile&3) = 32KB { A 256x32 | B 256x32 } bf16, XOR-swizzled.
// Staging: tile T+2 staged during tile T's 2 phases (2 HTs of 8KB per phase,
// = 2 load16/lane/phase). vmcnt(4) at each tile's last phase keeps exactly
// one tile's loads in flight; vmcnt(0) only once, before the last tile.
template <int K, int N, bool RELU, bool OUT_BF16>
__global__ __launch_bounds__(512, 2) void gemm_mlp(
    const u16* __restrict__ Amat, const u16* __restrict__ Wt,
    const float* __restrict__ bias, const int* __restrict__ seps,
    void* __restrict__ outp) {
    constexpr int BM = 256, BK = 32;
    constexpr int NT = K / BK;
    constexpr int NHT = 4 * NT;                // half-tile (8KB) stream length
    constexpr int NNB = N / 256;               // n-blocks per m-stripe (4 or 2)
    constexpr int LNB = (NNB == 4) ? 2 : 1;
    extern __shared__ u16 lds[];               // 128 KB dynamic

    const int tid = threadIdx.x;
    const int wave = tid >> 6, lane = tid & 63;
    const int wm = wave >> 2, wn = wave & 3;
    const int quad = lane >> 4, l16 = lane & 15;

    // XCD swizzle: HW maps block i -> XCD i%8; all NNB n-blocks of one
    // m-stripe are dispatch-adjacent and share i%8 -> one XCD's L2 holds
    // the A-stripe while its n-blocks run there.
    const int bidx = blockIdx.x;
    const int t = bidx >> 3;
    const int mb = (t >> LNB) * 8 + (bidx & 7);
    const int nb = t & (NNB - 1);
    const int m0 = mb * BM, n0 = nb * 256;

    const int s = seps[m0 >> 12];              // 4096 rows per agent
    const u16* Ab = Amat + (size_t)m0 * K;
    const u16* Bb = Wt + ((size_t)s * N + n0) * K;

    // staging: HT = 128 rows x 32 k (8KB). Wave w covers rows w*16..w*16+15;
    // lane L: row = w*16 + (L>>2), LDS chunk (L&3) <- global chunk
    // (L&3)^((L>>2)&3)  => LDS[row][cc] = global[cc ^ (row&3)] (XOR swizzle).
    const int soff = ((wave << 4) + (lane >> 2)) * K
                   + (((lane & 3) ^ ((lane >> 2) & 3)) << 3);
    u16* const ldsw = &lds[wave << 9];         // wave's 512-u16 chunk per HT

    auto STAGE = [&](int sh) {
        if (sh < NHT) {
            const int tl = sh >> 2, ht = sh & 3;   // ht: 0,1 = A halves; 2,3 = B
            const u16* g = (ht & 2) ? Bb : Ab;
            if (ht & 1) g += 128 * K;
            load16(g + tl * BK + soff, ldsw + ((tl & 3) << 14) + (ht << 12));
        }
    };

    floatx4 acc[8][4];
#pragma unroll
    for (int i = 0; i < 8; ++i)
#pragma unroll
        for (int j = 0; j < 4; ++j) acc[i][j] = (floatx4){0.f, 0.f, 0.f, 0.f};

    // prologue: stage tiles 0,1 (8 HTs); tile 0 landed, tile 1 may fly.
#pragma unroll
    for (int sh = 0; sh < 8; ++sh) STAGE(sh);
    asm volatile("s_waitcnt vmcnt(4)" ::: "memory");
    __builtin_amdgcn_s_barrier();

    const int aslot = (quad ^ (l16 & 3)) << 3; // de-swizzle: global chunk=quad
    const int arow = (wm << 7) + l16;
    const int brow = (wn << 6) + l16;

#pragma unroll 1
    for (int T = 0; T < NT; ++T) {
        const u16* buf = &lds[(T & 3) << 14];
        const int sb = (T + 2) << 2;           // stage tile T+2 (dead slot)
        bf16x8 bfr[4];
#pragma unroll
        for (int q = 0; q < 2; ++q) {          // phase: 16-MFMA C-half
            bf16x8 af[4];
#pragma unroll
            for (int i = 0; i < 4; ++i)
                af[i] = *(const bf16x8*)&buf[((arow + (q << 6) + (i << 4)) << 5) + aslot];
            if (q == 0) {                      // B frags live across both phases
#pragma unroll
                for (int nf = 0; nf < 4; ++nf)
                    bfr[nf] = *(const bf16x8*)&buf[8192 + ((brow + (nf << 4)) << 5) + aslot];
            }
            STAGE(sb + (q << 1));
            STAGE(sb + (q << 1) + 1);
            if (q == 1) {                      // once per K-tile, counted
                if (T < NT - 2) asm volatile("s_waitcnt vmcnt(4)" ::: "memory");
                else            asm volatile("s_waitcnt vmcnt(0)" ::: "memory");
            }
            __builtin_amdgcn_s_barrier();
            asm volatile("s_waitcnt lgkmcnt(0)" ::: "memory");
            __builtin_amdgcn_sched_barrier(0);
            __builtin_amdgcn_s_setprio(1);
#pragma unroll
            for (int i = 0; i < 4; ++i)
#pragma unroll
                for (int nf = 0; nf < 4; ++nf)
                    acc[(q << 2) + i][nf] = __builtin_amdgcn_mfma_f32_16x16x32_bf16(
                        af[i], bfr[nf], acc[(q << 2) + i][nf], 0, 0, 0);
            __builtin_amdgcn_s_setprio(0);
            __builtin_amdgcn_sched_barrier(0);
            __builtin_amdgcn_s_barrier();
        }
    }
    __syncthreads();   // all LDS traffic done before epilogue reuse

    // ---- epilogue: 8 mf-phases, LDS transpose, coalesced stores ----
    float* eps = (float*)lds;                  // [32][268] f32 per phase
    constexpr int EW = 268;
    float bv[4];
#pragma unroll
    for (int nf = 0; nf < 4; ++nf)
        bv[nf] = bias[s * N + n0 + (wn << 6) + (nf << 4) + l16];

    const int rL = tid & 63;                   // float4 column slot
    const int rw = tid >> 6;                   // row base

#pragma unroll
    for (int mf = 0; mf < 8; ++mf) {
#pragma unroll
        for (int nf = 0; nf < 4; ++nf)
#pragma unroll
            for (int r = 0; r < 4; ++r) {
                float v = acc[mf][nf][r] + bv[nf];
                if (RELU) v = fmaxf(v, 0.0f);
                eps[((wm << 4) + (quad << 2) + r) * EW + (wn << 6) + (nf << 4) + l16] = v;
            }
        __syncthreads();
#pragma unroll
        for (int j = 0; j < 4; ++j) {
            const int er = rw + (j << 3);      // 0..31
            const int grow = m0 + ((er >> 4) << 7) + (mf << 4) + (er & 15);
            const float4 v = *(const float4*)&eps[er * EW + (rL << 2)];
            if (OUT_BF16) {
                ushort4 o;
                o.x = f2bf(v.x); o.y = f2bf(v.y); o.z = f2bf(v.z); o.w = f2bf(v.w);
                *(ushort4*)((u16*)outp + (size_t)grow * N + n0 + (rL << 2)) = o;
            } else {
                *(float4*)((float*)outp + (size_t)grow * N + n0 + (rL << 2)) = v;
            }
        }
        __syncthreads();
    }
}

extern "C" void kernel_launch(void* const* d_in, const int* in_sizes, int n_in,
                              void* d_out, int out_size, void* d_ws, size_t ws_size,
                              hipStream_t stream) {
    const float* x  = (const float*)d_in[0];
    const float* W1 = (const float*)d_in[1];
    const float* b1 = (const float*)d_in[2];
    const float* W2 = (const float*)d_in[3];
    const float* b2 = (const float*)d_in[4];
    const float* W3 = (const float*)d_in[5];
    const float* b3 = (const float*)d_in[6];
    const int* seps = (const int*)d_in[7];

    char* ws = (char*)d_ws;
    u16* w1t = (u16*)(ws);                    //  2 MB: [4][1024][256]
    u16* w2t = (u16*)(ws + (2ull << 20));     //  8 MB: [4][1024][1024]
    u16* w3t = (u16*)(ws + (10ull << 20));    //  4 MB: [4][512][1024]
    u16* xb  = (u16*)(ws + (14ull << 20));    // 16 MB: [32768][256]
    u16* h1  = (u16*)(ws + (30ull << 20));    // 64 MB: [32768][1024]
    u16* h2  = (u16*)(ws + (94ull << 20));    // 64 MB: [32768][1024]

    // 128 KB dynamic LDS opt-in (host-side, graph-capture safe; once).
    static int attr_once = []() {
        auto k1 = gemm_mlp<256, 1024, true, true>;
        auto k2 = gemm_mlp<1024, 1024, true, true>;
        auto k3 = gemm_mlp<1024, 512, false, false>;
        hipFuncSetAttribute(reinterpret_cast<const void*>(k1),
                            hipFuncAttributeMaxDynamicSharedMemorySize, 131072);
        hipFuncSetAttribute(reinterpret_cast<const void*>(k2),
                            hipFuncAttributeMaxDynamicSharedMemorySize, 131072);
        hipFuncSetAttribute(reinterpret_cast<const void*>(k3),
                            hipFuncAttributeMaxDynamicSharedMemorySize, 131072);
        return 0;
    }();
    (void)attr_once;

    prep<<<15360, 256, 0, stream>>>(x, xb, W1, w1t, W2, w2t, W3, w3t);

    // L1: [32768,256]@[256,1024]^T +b1, relu -> h1 (bf16)
    gemm_mlp<256, 1024, true, true><<<512, 512, 131072, stream>>>(xb, w1t, b1, seps, h1);
    // L2: [32768,1024]@[1024,1024]^T +b2, relu -> h2 (bf16)
    gemm_mlp<1024, 1024, true, true><<<512, 512, 131072, stream>>>(h1, w2t, b2, seps, h2);
    // L3: [32768,1024]@[1024,512]^T +b3 -> out (f32)
    gemm_mlp<1024, 512, false, false><<<256, 512, 131072, stream>>>(h2, w3t, b3, seps, d_out);
}

// Round 2
// 265.156 us; speedup vs baseline: 1.0484x; 1.0484x over previous
//
#include <hip/hip_runtime.h>
#include <hip/hip_bf16.h>

// MultiAgentSEPSNetwork: A=8 agents, E=4096, O=256, H1=H2=1024, H3=512, S=4.
// M = A*E = 32768 rows. Only the seps_idx-selected net per agent is computed.
//
// R10: fix R9's regression. R9 (256x256, BK=32, ring-4) introduced a uniform
// 4-way LDS bank conflict (SQ_LDS_BANK_CONFLICT = 6.29M = exactly 4 cyc on
// every one of 1.57M ds_read_b128): 64B rows span only 16 banks, the
// chunk^(row&3) swizzle aliases lanes {0,4,8,12} per quad. Fix = BK=64
// (128B rows, 8 chunks = all 32 banks) with R8's measured-zero-conflict
// swizzle chunk^(l16&7), double-buffered 2x64KB (same 128KB LDS, m201
// geometry). Schedule: 4 phases/K-tile, 16 MFMA each (m-half x n-half x
// 2 k-steps), B-frags reused across phases (A0B0->A0B1->A1B1->A1B0) ->
// 24 ds_read_b128/wave/K-tile. All 8 next-tile staging DMAs burst at
// phase 0; single per-tile vmcnt(0) after phase 3's MFMA cluster (~600cy
// issue-to-drain cover). setprio(1) around each MFMA cluster (T5),
// lgkmcnt(0)+sched_barrier(0) fence per rule 18.
// Kept: XCD-swizzled grid, fused prep, coalesced LDS-transpose epilogue.

typedef unsigned short u16;
typedef __bf16 bf16x8 __attribute__((ext_vector_type(8)));
typedef float floatx4 __attribute__((ext_vector_type(4)));

__device__ __forceinline__ u16 f2bf(float f) {
    union { float f; unsigned int u; } v; v.f = f;
    unsigned int u = v.u;
    return (u16)((u + 0x7FFFu + ((u >> 16) & 1u)) >> 16);
}

// global -> LDS direct DMA, 16 B/lane. LDS dest = wave-uniform base + lane*16.
__device__ __forceinline__ void load16(const void* g, void* l) {
    __builtin_amdgcn_global_load_lds(
        (const __attribute__((address_space(1))) void*)(unsigned long long)g,
        (__attribute__((address_space(3))) void*)(unsigned int)(unsigned long long)l,
        16, 0, 0);
}

// ---------------- fused prep: x->bf16 + 3 weight transposes ----------------
__global__ __launch_bounds__(256) void prep(
    const float* __restrict__ x, u16* __restrict__ xb,
    const float* __restrict__ W1, u16* __restrict__ w1t,
    const float* __restrict__ W2, u16* __restrict__ w2t,
    const float* __restrict__ W3, u16* __restrict__ w3t) {
    __shared__ float tile[32][33];
    int b = blockIdx.x;
    const int tid = threadIdx.x;
    if (b < 8192) {
        int i = (b * 256 + tid) * 4;
        float4 v = *(const float4*)(x + i);
        ushort4 o;
        o.x = f2bf(v.x); o.y = f2bf(v.y); o.z = f2bf(v.z); o.w = f2bf(v.w);
        *(ushort4*)(xb + i) = o;
        return;
    }
    b -= 8192;
    const float* src; u16* dst; int K, N, n0, k0, s;
    if (b < 1024) {                     // W1 [4][256][1024] -> [4][1024][256]
        s = b >> 8; int r = b & 255;
        K = 256; N = 1024; n0 = (r & 31) * 32; k0 = (r >> 5) * 32;
        src = W1; dst = w1t;
    } else if (b < 5120) {              // W2 [4][1024][1024] -> same^T
        b -= 1024; s = b >> 10; int r = b & 1023;
        K = 1024; N = 1024; n0 = (r & 31) * 32; k0 = (r >> 5) * 32;
        src = W2; dst = w2t;
    } else {                            // W3 [4][1024][512] -> [4][512][1024]
        b -= 5120; s = b >> 9; int r = b & 511;
        K = 1024; N = 512; n0 = (r & 15) * 32; k0 = (r >> 4) * 32;
        src = W3; dst = w3t;
    }
    src += (size_t)s * K * N;
    dst += (size_t)s * N * K;
    const int tx = tid & 31, ty = tid >> 5;
#pragma unroll
    for (int j = 0; j < 32; j += 8)
        tile[ty + j][tx] = src[(size_t)(k0 + ty + j) * N + (n0 + tx)];
    __syncthreads();
#pragma unroll
    for (int j = 0; j < 32; j += 8)
        dst[(size_t)(n0 + ty + j) * K + (k0 + tx)] = f2bf(tile[tx][ty + j]);
}

// ---- fragment-load / MFMA-phase building blocks (compile-time H/V) ----
#define LDA(H)                                                                 \
    {                                                                          \
        _Pragma("unroll") for (int i = 0; i < 4; ++i)                          \
            _Pragma("unroll") for (int kk = 0; kk < 2; ++kk)                   \
                af[i][kk] = *(const bf16x8*)&buf[arow0 + ((H) << 12) +         \
                                                 (i << 10) + cs[kk]];          \
    }

#define LDB(V, BF)                                                             \
    {                                                                          \
        _Pragma("unroll") for (int j = 0; j < 2; ++j)                          \
            _Pragma("unroll") for (int kk = 0; kk < 2; ++kk)                   \
                BF[j][kk] = *(const bf16x8*)&buf[16384 + brow0 +               \
                                                 ((((V) << 1) + j) << 10) +    \
                                                 cs[kk]];                      \
    }

#define PHASE(H, V, BF, VM)                                                    \
    {                                                                          \
        __builtin_amdgcn_s_barrier();                                          \
        asm volatile("s_waitcnt lgkmcnt(0)" ::: "memory");                     \
        __builtin_amdgcn_sched_barrier(0);                                     \
        __builtin_amdgcn_s_setprio(1);                                         \
        _Pragma("unroll") for (int i = 0; i < 4; ++i)                          \
            _Pragma("unroll") for (int j = 0; j < 2; ++j)                      \
                _Pragma("unroll") for (int kk = 0; kk < 2; ++kk)               \
                    acc[((H) << 2) + i][((V) << 1) + j] =                      \
                        __builtin_amdgcn_mfma_f32_16x16x32_bf16(               \
                            af[i][kk], BF[j][kk],                              \
                            acc[((H) << 2) + i][((V) << 1) + j], 0, 0, 0);     \
        __builtin_amdgcn_s_setprio(0);                                         \
        __builtin_amdgcn_sched_barrier(0);                                     \
        if (VM) asm volatile("s_waitcnt vmcnt(0)" ::: "memory");               \
        __builtin_amdgcn_s_barrier();                                          \
    }

// ------------- grouped GEMM: 256x256, BK=64, dbuf, 4-phase K-tile -------------
// C[m,n] = act(A[M,K] @ Wt[s][N,K]^T + bias[s][N]);  s = seps[agent(m)]
// 512 thr = 8 waves (2M x 4N); per-wave C = 128x64 (acc 8x4); 16x16x32 MFMA.
// LDS: 2 buffers x {A 256x64 | B 256x64} bf16 = 2 x 64KB. 128B rows,
// chunk ^ (l16&7) swizzle (R8-proven, 0 conflicts).
template <int K, int N, bool RELU, bool OUT_BF16>
__global__ __launch_bounds__(512, 2) void gemm_mlp(
    const u16* __restrict__ Amat, const u16* __restrict__ Wt,
    const float* __restrict__ bias, const int* __restrict__ seps,
    void* __restrict__ outp) {
    constexpr int BK = 64;
    constexpr int NT = K / BK;
    constexpr int NNB = N / 256;               // n-blocks per m-stripe (4 or 2)
    constexpr int LNB = (NNB == 4) ? 2 : 1;
    extern __shared__ u16 lds[];               // 128 KB dynamic

    const int tid = threadIdx.x;
    const int wave = tid >> 6, lane = tid & 63;
    const int wm = wave >> 2, wn = wave & 3;
    const int quad = lane >> 4, l16 = lane & 15;

    // XCD swizzle: block i -> XCD i%8; all NNB n-blocks of one m-stripe are
    // dispatch-adjacent and share i%8 -> one XCD's L2 holds the A-stripe.
    const int bidx = blockIdx.x;
    const int t = bidx >> 3;
    const int mb = (t >> LNB) * 8 + (bidx & 7);
    const int nb = t & (NNB - 1);
    const int m0 = mb * 256, n0 = nb * 256;

    const int s = seps[m0 >> 12];              // 4096 rows per agent
    const u16* Ab = Amat + (size_t)m0 * K;
    const u16* Bb = Wt + ((size_t)s * N + n0) * K;

    // staging: per call, 8 waves x 8 rows x 128B = 64 rows. Lane L of wave w:
    // row = w*8 + (L>>3), LDS slot L&7 <- global chunk (L&7)^(L>>3)
    // => LDS[r][c] = G[r][c ^ (r&7)]  (R8 swizzle; involution on read).
    const int srow = (wave << 3) + (lane >> 3);
    const int sch = ((lane & 7) ^ (lane >> 3)) << 3;
    const u16* gA = Ab + (size_t)srow * K + sch;
    const u16* gB = Bb + (size_t)srow * K + sch;
    const unsigned lsw = (unsigned)(wave << 9);   // wave*8 rows * 64 u16

    auto STAGE = [&](int T1) {
        u16* dbuf = &lds[(T1 & 1) << 15];      // 32768 u16 per buffer
        const int k0 = T1 * BK;
#pragma unroll
        for (int cj = 0; cj < 4; ++cj) {
            load16(gA + (size_t)(cj << 6) * K + k0, dbuf + (cj << 12) + lsw);
            load16(gB + (size_t)(cj << 6) * K + k0,
                   dbuf + 16384 + (cj << 12) + lsw);
        }
    };

    // fragment read bases (u16 index): row stride 64 u16 = 128 B.
    // A row = wm*128 + H*64 + i*16 + l16; chunk g = kk*4+quad, de-swizzle
    // slot = g ^ (l16&7)  (row&7 == l16&7 since rows step by 16).
    const int arow0 = ((wm << 7) + l16) << 6;
    const int brow0 = ((wn << 6) + l16) << 6;
    int cs[2];
    cs[0] = ((quad ^ (l16 & 7)) << 3);
    cs[1] = (((4 + quad) ^ (l16 & 7)) << 3);

    floatx4 acc[8][4];
#pragma unroll
    for (int i = 0; i < 8; ++i)
#pragma unroll
        for (int j = 0; j < 4; ++j) acc[i][j] = (floatx4){0.f, 0.f, 0.f, 0.f};

    // prologue: stage tile 0, drain, sync.
    STAGE(0);
    asm volatile("s_waitcnt vmcnt(0)" ::: "memory");
    __builtin_amdgcn_s_barrier();

    bf16x8 af[4][2], bf0[2][2], bf1[2][2];

#pragma unroll 1
    for (int T = 0; T < NT; ++T) {
        const u16* buf = &lds[(T & 1) << 15];
        const bool more = (T + 1 < NT);

        // phase 0: (h0,v0) — load A0 (8 reads) + B0 (4 reads); burst-issue
        // all 8 staging DMAs for tile T+1 into the dead buffer.
        LDA(0);
        LDB(0, bf0);
        if (more) STAGE(T + 1);
        PHASE(0, 0, bf0, false);
        // phase 1: (h0,v1) — load B1 (4 reads), reuse A0.
        LDB(1, bf1);
        PHASE(0, 1, bf1, false);
        // phase 2: (h1,v1) — load A1 (8 reads), reuse B1.
        LDA(1);
        PHASE(1, 1, bf1, false);
        // phase 3: (h1,v0) — reuse A1 + B0; drain next-tile staging after
        // the MFMA cluster (issue-to-drain ~3.5 phases).
        PHASE(1, 0, bf0, more);
    }
    __syncthreads();   // all LDS traffic done before epilogue reuse

    // ---- epilogue: 8 mf-phases, LDS transpose, coalesced stores ----
    float* eps = (float*)lds;                  // [32][268] f32 per phase
    constexpr int EW = 268;
    float bv[4];
#pragma unroll
    for (int nf = 0; nf < 4; ++nf)
        bv[nf] = bias[s * N + n0 + (wn << 6) + (nf << 4) + l16];

    const int rL = tid & 63;                   // float4 column slot
    const int rw = tid >> 6;                   // row base

#pragma unroll
    for (int mf = 0; mf < 8; ++mf) {
#pragma unroll
        for (int nf = 0; nf < 4; ++nf)
#pragma unroll
            for (int r = 0; r < 4; ++r) {
                float v = acc[mf][nf][r] + bv[nf];
                if (RELU) v = fmaxf(v, 0.0f);
                eps[((wm << 4) + (quad << 2) + r) * EW + (wn << 6) + (nf << 4) + l16] = v;
            }
        __syncthreads();
#pragma unroll
        for (int j = 0; j < 4; ++j) {
            const int er = rw + (j << 3);      // 0..31
            const int grow = m0 + ((er >> 4) << 7) + (mf << 4) + (er & 15);
            const float4 v = *(const float4*)&eps[er * EW + (rL << 2)];
            if (OUT_BF16) {
                ushort4 o;
                o.x = f2bf(v.x); o.y = f2bf(v.y); o.z = f2bf(v.z); o.w = f2bf(v.w);
                *(ushort4*)((u16*)outp + (size_t)grow * N + n0 + (rL << 2)) = o;
            } else {
                *(float4*)((float*)outp + (size_t)grow * N + n0 + (rL << 2)) = v;
            }
        }
        __syncthreads();
    }
}

extern "C" void kernel_launch(void* const* d_in, const int* in_sizes, int n_in,
                              void* d_out, int out_size, void* d_ws, size_t ws_size,
                              hipStream_t stream) {
    const float* x  = (const float*)d_in[0];
    const float* W1 = (const float*)d_in[1];
    const float* b1 = (const float*)d_in[2];
    const float* W2 = (const float*)d_in[3];
    const float* b2 = (const float*)d_in[4];
    const float* W3 = (const float*)d_in[5];
    const float* b3 = (const float*)d_in[6];
    const int* seps = (const int*)d_in[7];

    char* ws = (char*)d_ws;
    u16* w1t = (u16*)(ws);                    //  2 MB: [4][1024][256]
    u16* w2t = (u16*)(ws + (2ull << 20));     //  8 MB: [4][1024][1024]
    u16* w3t = (u16*)(ws + (10ull << 20));    //  4 MB: [4][512][1024]
    u16* xb  = (u16*)(ws + (14ull << 20));    // 16 MB: [32768][256]
    u16* h1  = (u16*)(ws + (30ull << 20));    // 64 MB: [32768][1024]
    u16* h2  = (u16*)(ws + (94ull << 20));    // 64 MB: [32768][1024]

    // 128 KB dynamic LDS opt-in (host-side, once).
    static int attr_once = []() {
        auto k1 = gemm_mlp<256, 1024, true, true>;
        auto k2 = gemm_mlp<1024, 1024, true, true>;
        auto k3 = gemm_mlp<1024, 512, false, false>;
        hipFuncSetAttribute(reinterpret_cast<const void*>(k1),
                            hipFuncAttributeMaxDynamicSharedMemorySize, 131072);
        hipFuncSetAttribute(reinterpret_cast<const void*>(k2),
                            hipFuncAttributeMaxDynamicSharedMemorySize, 131072);
        hipFuncSetAttribute(reinterpret_cast<const void*>(k3),
                            hipFuncAttributeMaxDynamicSharedMemorySize, 131072);
        return 0;
    }();
    (void)attr_once;

    prep<<<15360, 256, 0, stream>>>(x, xb, W1, w1t, W2, w2t, W3, w3t);

    // L1: [32768,256]@[256,1024]^T +b1, relu -> h1 (bf16)
    gemm_mlp<256, 1024, true, true><<<512, 512, 131072, stream>>>(xb, w1t, b1, seps, h1);
    // L2: [32768,1024]@[1024,1024]^T +b2, relu -> h2 (bf16)
    gemm_mlp<1024, 1024, true, true><<<512, 512, 131072, stream>>>(h1, w2t, b2, seps, h2);
    // L3: [32768,1024]@[1024,512]^T +b3 -> out (f32)
    gemm_mlp<1024, 512, false, false><<<256, 512, 131072, stream>>>(h2, w3t, b3, seps, d_out);
}

// Round 4
// 261.108 us; speedup vs baseline: 1.0647x; 1.0155x over previous
//
#include <hip/hip_runtime.h>
#include <hip/hip_bf16.h>

// MultiAgentSEPSNetwork: A=8 agents, E=4096, O=256, H1=H2=1024, H3=512, S=4.
// M = A*E = 32768 rows. Only the seps_idx-selected net per agent is computed.
//
// R12: R11's 1-barrier counted-vmcnt schedule FAILED correctness (absmax 0.64)
// despite clean paper accounting -> m152 lesson: sync-structure edits race in
// non-obvious ways. Revert to R10's PROVEN-SAFE sync skeleton (2 barriers per
// phase, vmcnt(0) drain before the end-of-tile barrier; passed @0.03125) and
// remove only its compile-time poison:
//  - DROP sched_barrier(0) pins (m141: order-pinning costs ~40%).
//  - DROP asm lgkmcnt(0) full drain: fragment ds_reads are compiler-visible,
//    hipcc emits fine-grained lgkmcnt so MFMAs start as operands land.
//  - SPLIT the 8-DMA staging burst 4+4 across ph0/ph1 pre-windows: >=2.5
//    windows of slack before ph3's vmcnt(0) -> drain finds loads landed
//    (counted-vmcnt benefit, drain-semantics safety).
// Geometry unchanged from R10 (verified): 256x256, BK=64, dbuf 2x64KB,
// 4 quadrant-phases x 16 MFMA, zero-conflict chunk^(l16&7) swizzle,
// XCD-swizzled grid, setprio around MFMA clusters, LDS-transpose epilogue.

typedef unsigned short u16;
typedef __bf16 bf16x8 __attribute__((ext_vector_type(8)));
typedef float floatx4 __attribute__((ext_vector_type(4)));

__device__ __forceinline__ u16 f2bf(float f) {
    union { float f; unsigned int u; } v; v.f = f;
    unsigned int u = v.u;
    return (u16)((u + 0x7FFFu + ((u >> 16) & 1u)) >> 16);
}

// global -> LDS direct DMA, 16 B/lane. LDS dest = wave-uniform base + lane*16.
__device__ __forceinline__ void load16(const void* g, void* l) {
    __builtin_amdgcn_global_load_lds(
        (const __attribute__((address_space(1))) void*)(unsigned long long)g,
        (__attribute__((address_space(3))) void*)(unsigned int)(unsigned long long)l,
        16, 0, 0);
}

// ---------------- fused prep: x->bf16 + 3 weight transposes ----------------
__global__ __launch_bounds__(256) void prep(
    const float* __restrict__ x, u16* __restrict__ xb,
    const float* __restrict__ W1, u16* __restrict__ w1t,
    const float* __restrict__ W2, u16* __restrict__ w2t,
    const float* __restrict__ W3, u16* __restrict__ w3t) {
    __shared__ float tile[32][33];
    int b = blockIdx.x;
    const int tid = threadIdx.x;
    if (b < 8192) {
        int i = (b * 256 + tid) * 4;
        float4 v = *(const float4*)(x + i);
        ushort4 o;
        o.x = f2bf(v.x); o.y = f2bf(v.y); o.z = f2bf(v.z); o.w = f2bf(v.w);
        *(ushort4*)(xb + i) = o;
        return;
    }
    b -= 8192;
    const float* src; u16* dst; int K, N, n0, k0, s;
    if (b < 1024) {                     // W1 [4][256][1024] -> [4][1024][256]
        s = b >> 8; int r = b & 255;
        K = 256; N = 1024; n0 = (r & 31) * 32; k0 = (r >> 5) * 32;
        src = W1; dst = w1t;
    } else if (b < 5120) {              // W2 [4][1024][1024] -> same^T
        b -= 1024; s = b >> 10; int r = b & 1023;
        K = 1024; N = 1024; n0 = (r & 31) * 32; k0 = (r >> 5) * 32;
        src = W2; dst = w2t;
    } else {                            // W3 [4][1024][512] -> [4][512][1024]
        b -= 5120; s = b >> 9; int r = b & 511;
        K = 1024; N = 512; n0 = (r & 15) * 32; k0 = (r >> 4) * 32;
        src = W3; dst = w3t;
    }
    src += (size_t)s * K * N;
    dst += (size_t)s * N * K;
    const int tx = tid & 31, ty = tid >> 5;
#pragma unroll
    for (int j = 0; j < 32; j += 8)
        tile[ty + j][tx] = src[(size_t)(k0 + ty + j) * N + (n0 + tx)];
    __syncthreads();
#pragma unroll
    for (int j = 0; j < 32; j += 8)
        dst[(size_t)(n0 + ty + j) * K + (k0 + tx)] = f2bf(tile[tx][ty + j]);
}

// ---- fragment-load / MFMA-phase building blocks (compile-time H/V) ----
#define LDA(H)                                                                 \
    {                                                                          \
        _Pragma("unroll") for (int i = 0; i < 4; ++i)                          \
            _Pragma("unroll") for (int kk = 0; kk < 2; ++kk)                   \
                af[i][kk] = *(const bf16x8*)&buf[arow0 + ((H) << 12) +         \
                                                 (i << 10) + cs[kk]];          \
    }

#define LDB(V, BF)                                                             \
    {                                                                          \
        _Pragma("unroll") for (int j = 0; j < 2; ++j)                          \
            _Pragma("unroll") for (int kk = 0; kk < 2; ++kk)                   \
                BF[j][kk] = *(const bf16x8*)&buf[16384 + brow0 +               \
                                                 ((((V) << 1) + j) << 10) +    \
                                                 cs[kk]];                      \
    }

// R10's proven-safe phase: barrier | MFMA cluster (compiler-scheduled
// fine-grained lgkm waits) | optional vmcnt(0) drain | barrier.
// No lgkmcnt(0) drain, no sched_barrier pins.
#define PHASE(H, V, BF, VM)                                                    \
    {                                                                          \
        __builtin_amdgcn_s_barrier();                                          \
        __builtin_amdgcn_s_setprio(1);                                         \
        _Pragma("unroll") for (int i = 0; i < 4; ++i)                          \
            _Pragma("unroll") for (int j = 0; j < 2; ++j)                      \
                _Pragma("unroll") for (int kk = 0; kk < 2; ++kk)               \
                    acc[((H) << 2) + i][((V) << 1) + j] =                      \
                        __builtin_amdgcn_mfma_f32_16x16x32_bf16(               \
                            af[i][kk], BF[j][kk],                              \
                            acc[((H) << 2) + i][((V) << 1) + j], 0, 0, 0);     \
        __builtin_amdgcn_s_setprio(0);                                         \
        if (VM) asm volatile("s_waitcnt vmcnt(0)" ::: "memory");               \
        __builtin_amdgcn_s_barrier();                                          \
    }

// ------------- grouped GEMM: 256x256, BK=64, dbuf, 4-phase K-tile -------------
// C[m,n] = act(A[M,K] @ Wt[s][N,K]^T + bias[s][N]);  s = seps[agent(m)]
// 512 thr = 8 waves (2M x 4N); per-wave C = 128x64 (acc 8x4); 16x16x32 MFMA.
// LDS: 2 buffers x {A 256x64 | B 256x64} bf16 = 2 x 64KB. 128B rows,
// chunk ^ (l16&7) swizzle (0 conflicts, verified R10).
template <int K, int N, bool RELU, bool OUT_BF16>
__global__ __launch_bounds__(512, 2) void gemm_mlp(
    const u16* __restrict__ Amat, const u16* __restrict__ Wt,
    const float* __restrict__ bias, const int* __restrict__ seps,
    void* __restrict__ outp) {
    constexpr int BK = 64;
    constexpr int NT = K / BK;
    constexpr int NNB = N / 256;               // n-blocks per m-stripe (4 or 2)
    constexpr int LNB = (NNB == 4) ? 2 : 1;
    extern __shared__ u16 lds[];               // 128 KB dynamic

    const int tid = threadIdx.x;
    const int wave = tid >> 6, lane = tid & 63;
    const int wm = wave >> 2, wn = wave & 3;
    const int quad = lane >> 4, l16 = lane & 15;

    // XCD swizzle: block i -> XCD i%8; all NNB n-blocks of one m-stripe are
    // dispatch-adjacent and share i%8 -> one XCD's L2 holds the A-stripe.
    const int bidx = blockIdx.x;
    const int t = bidx >> 3;
    const int mb = (t >> LNB) * 8 + (bidx & 7);
    const int nb = t & (NNB - 1);
    const int m0 = mb * 256, n0 = nb * 256;

    const int s = seps[m0 >> 12];              // 4096 rows per agent
    const u16* Ab = Amat + (size_t)m0 * K;
    const u16* Bb = Wt + ((size_t)s * N + n0) * K;

    // staging: half-tile (128 rows x 64 k) per STAGEH = 2 load16/thread.
    // Wave w, lane L: row = w*8 + (L>>3), LDS slot L&7 <- global chunk
    // (L&7)^(L>>3)  => LDS[r][c] = G[r][c ^ (r&7)]  (involution on read).
    const int srow = (wave << 3) + (lane >> 3);
    const int sch = ((lane & 7) ^ (lane >> 3)) << 3;
    const u16* gA = Ab + (size_t)srow * K + sch;
    const u16* gB = Bb + (size_t)srow * K + sch;
    const unsigned lsw = (unsigned)(wave << 9);   // wave*8 rows * 64 u16

    // ht: 0=A rows[0,128) 1=A rows[128,256) 2=B rows[0,128) 3=B rows[128,256)
    auto STAGEH = [&](int T1, int ht) {
        u16* dbuf = &lds[(T1 & 1) << 15];      // 32768 u16 per buffer
        const int k0 = T1 * BK;
        const u16* g = (ht & 2) ? gB : gA;
        const int r0 = (ht & 1) << 7;
#pragma unroll
        for (int q = 0; q < 2; ++q)
            load16(g + (size_t)(r0 + (q << 6)) * K + k0,
                   dbuf + ht * 8192 + (q << 12) + lsw);
    };

    // fragment read bases (u16 index): row stride 64 u16 = 128 B.
    // de-swizzle slot = chunk ^ (l16&7)  (row&7 == l16&7, rows step by 16).
    const int arow0 = ((wm << 7) + l16) << 6;
    const int brow0 = ((wn << 6) + l16) << 6;
    int cs[2];
    cs[0] = ((quad ^ (l16 & 7)) << 3);
    cs[1] = (((4 + quad) ^ (l16 & 7)) << 3);

    floatx4 acc[8][4];
#pragma unroll
    for (int i = 0; i < 8; ++i)
#pragma unroll
        for (int j = 0; j < 4; ++j) acc[i][j] = (floatx4){0.f, 0.f, 0.f, 0.f};

    // prologue: stage tile 0 fully, drain, publish.
    STAGEH(0, 0); STAGEH(0, 2); STAGEH(0, 3); STAGEH(0, 1);
    asm volatile("s_waitcnt vmcnt(0)" ::: "memory");
    __builtin_amdgcn_s_barrier();

    bf16x8 af[4][2], bf0[2][2], bf1[2][2];

#pragma unroll 1
    for (int T = 0; T < NT; ++T) {
        const u16* buf = &lds[(T & 1) << 15];
        const bool more = (T + 1 < NT);

        // ph0: quadrant (A0,B0); stage A-lo,B-lo of tile T+1.
        LDA(0); LDB(0, bf0);
        if (more) { STAGEH(T + 1, 0); STAGEH(T + 1, 2); }
        PHASE(0, 0, bf0, false);
        // ph1: quadrant (A0,B1); stage B-hi,A-hi of tile T+1.
        LDB(1, bf1);
        if (more) { STAGEH(T + 1, 3); STAGEH(T + 1, 1); }
        PHASE(0, 1, bf1, false);
        // ph2: quadrant (A1,B1); no staging.
        LDA(1);
        PHASE(1, 1, bf1, false);
        // ph3: quadrant (A1,B0); drain staging (issued >=2 windows ago)
        // before the end-of-tile barrier that publishes buffer T+1.
        PHASE(1, 0, bf0, more);
    }
    __syncthreads();   // all LDS traffic done before epilogue reuse

    // ---- epilogue: 8 mf-phases, LDS transpose, coalesced stores ----
    float* eps = (float*)lds;                  // [32][268] f32 per phase
    constexpr int EW = 268;
    float bv[4];
#pragma unroll
    for (int nf = 0; nf < 4; ++nf)
        bv[nf] = bias[s * N + n0 + (wn << 6) + (nf << 4) + l16];

    const int rL = tid & 63;                   // float4 column slot
    const int rw = tid >> 6;                   // row base

#pragma unroll
    for (int mf = 0; mf < 8; ++mf) {
#pragma unroll
        for (int nf = 0; nf < 4; ++nf)
#pragma unroll
            for (int r = 0; r < 4; ++r) {
                float v = acc[mf][nf][r] + bv[nf];
                if (RELU) v = fmaxf(v, 0.0f);
                eps[((wm << 4) + (quad << 2) + r) * EW + (wn << 6) + (nf << 4) + l16] = v;
            }
        __syncthreads();
#pragma unroll
        for (int j = 0; j < 4; ++j) {
            const int er = rw + (j << 3);      // 0..31
            const int grow = m0 + ((er >> 4) << 7) + (mf << 4) + (er & 15);
            const float4 v = *(const float4*)&eps[er * EW + (rL << 2)];
            if (OUT_BF16) {
                ushort4 o;
                o.x = f2bf(v.x); o.y = f2bf(v.y); o.z = f2bf(v.z); o.w = f2bf(v.w);
                *(ushort4*)((u16*)outp + (size_t)grow * N + n0 + (rL << 2)) = o;
            } else {
                *(float4*)((float*)outp + (size_t)grow * N + n0 + (rL << 2)) = v;
            }
        }
        __syncthreads();
    }
}

extern "C" void kernel_launch(void* const* d_in, const int* in_sizes, int n_in,
                              void* d_out, int out_size, void* d_ws, size_t ws_size,
                              hipStream_t stream) {
    const float* x  = (const float*)d_in[0];
    const float* W1 = (const float*)d_in[1];
    const float* b1 = (const float*)d_in[2];
    const float* W2 = (const float*)d_in[3];
    const float* b2 = (const float*)d_in[4];
    const float* W3 = (const float*)d_in[5];
    const float* b3 = (const float*)d_in[6];
    const int* seps = (const int*)d_in[7];

    char* ws = (char*)d_ws;
    u16* w1t = (u16*)(ws);                    //  2 MB: [4][1024][256]
    u16* w2t = (u16*)(ws + (2ull << 20));     //  8 MB: [4][1024][1024]
    u16* w3t = (u16*)(ws + (10ull << 20));    //  4 MB: [4][512][1024]
    u16* xb  = (u16*)(ws + (14ull << 20));    // 16 MB: [32768][256]
    u16* h1  = (u16*)(ws + (30ull << 20));    // 64 MB: [32768][1024]
    u16* h2  = (u16*)(ws + (94ull << 20));    // 64 MB: [32768][1024]

    // 128 KB dynamic LDS opt-in (host-side, once).
    static int attr_once = []() {
        auto k1 = gemm_mlp<256, 1024, true, true>;
        auto k2 = gemm_mlp<1024, 1024, true, true>;
        auto k3 = gemm_mlp<1024, 512, false, false>;
        hipFuncSetAttribute(reinterpret_cast<const void*>(k1),
                            hipFuncAttributeMaxDynamicSharedMemorySize, 131072);
        hipFuncSetAttribute(reinterpret_cast<const void*>(k2),
                            hipFuncAttributeMaxDynamicSharedMemorySize, 131072);
        hipFuncSetAttribute(reinterpret_cast<const void*>(k3),
                            hipFuncAttributeMaxDynamicSharedMemorySize, 131072);
        return 0;
    }();
    (void)attr_once;

    prep<<<15360, 256, 0, stream>>>(x, xb, W1, w1t, W2, w2t, W3, w3t);

    // L1: [32768,256]@[256,1024]^T +b1, relu -> h1 (bf16)
    gemm_mlp<256, 1024, true, true><<<512, 512, 131072, stream>>>(xb, w1t, b1, seps, h1);
    // L2: [32768,1024]@[1024,1024]^T +b2, relu -> h2 (bf16)
    gemm_mlp<1024, 1024, true, true><<<512, 512, 131072, stream>>>(h1, w2t, b2, seps, h2);
    // L3: [32768,1024]@[1024,512]^T +b3 -> out (f32)
    gemm_mlp<1024, 512, false, false><<<256, 512, 131072, stream>>>(h2, w3t, b3, seps, d_out);
}

// Round 5
// 253.613 us; speedup vs baseline: 1.0961x; 1.0296x over previous
//
#include <hip/hip_runtime.h>
#include <hip/hip_bf16.h>

// MultiAgentSEPSNetwork: A=8 agents, E=4096, O=256, H1=H2=1024, H3=512, S=4.
// M = A*E = 32768 rows. Only the seps_idx-selected net per agent is computed.
//
// R13: R12 (2 barriers/phase) measured 6750 cyc/tile vs 2483 MFMA + 2304 LDS
// ideal -> the read-window/MFMA-window lockstep serializes both pipes across
// all 8 waves (1 block/CU at 128KB LDS; MfmaUtil ceiling 37% == measured 30%).
// Change ONE thing: single barrier per phase (R9-proven sync shape):
//   {reads || stage} -> s_barrier -> lgkmcnt(0)+sched_barrier(0) pin ->
//   setprio(1) 16xMFMA setprio(0)
// so window p holds MFMA_p of some waves and reads_{p+1}+staging of others ->
// LDS pipe and MFMA pipe overlap across waves. The lgkm0 pin after each
// barrier is the race-safety keystone (R11 failed without it: hipcc sinks
// register-only MFMAs past raw barriers, leaving ds_reads pending when the
// next tile's DMA overwrites the buffer; R9 passed with it).
// Kept from R12 (verified): 256x256, BK=64, dbuf 2x64KB, quadrant phases,
// staging 4+4 at ph0/ph1, vmcnt(0) publish at ph3 (~3 windows after last
// issue), zero-conflict chunk^(l16&7) swizzle, XCD grid swizzle,
// LDS-transpose epilogue.

typedef unsigned short u16;
typedef __bf16 bf16x8 __attribute__((ext_vector_type(8)));
typedef float floatx4 __attribute__((ext_vector_type(4)));

__device__ __forceinline__ u16 f2bf(float f) {
    union { float f; unsigned int u; } v; v.f = f;
    unsigned int u = v.u;
    return (u16)((u + 0x7FFFu + ((u >> 16) & 1u)) >> 16);
}

// global -> LDS direct DMA, 16 B/lane. LDS dest = wave-uniform base + lane*16.
__device__ __forceinline__ void load16(const void* g, void* l) {
    __builtin_amdgcn_global_load_lds(
        (const __attribute__((address_space(1))) void*)(unsigned long long)g,
        (__attribute__((address_space(3))) void*)(unsigned int)(unsigned long long)l,
        16, 0, 0);
}

// ---------------- fused prep: x->bf16 + 3 weight transposes ----------------
__global__ __launch_bounds__(256) void prep(
    const float* __restrict__ x, u16* __restrict__ xb,
    const float* __restrict__ W1, u16* __restrict__ w1t,
    const float* __restrict__ W2, u16* __restrict__ w2t,
    const float* __restrict__ W3, u16* __restrict__ w3t) {
    __shared__ float tile[32][33];
    int b = blockIdx.x;
    const int tid = threadIdx.x;
    if (b < 8192) {
        int i = (b * 256 + tid) * 4;
        float4 v = *(const float4*)(x + i);
        ushort4 o;
        o.x = f2bf(v.x); o.y = f2bf(v.y); o.z = f2bf(v.z); o.w = f2bf(v.w);
        *(ushort4*)(xb + i) = o;
        return;
    }
    b -= 8192;
    const float* src; u16* dst; int K, N, n0, k0, s;
    if (b < 1024) {                     // W1 [4][256][1024] -> [4][1024][256]
        s = b >> 8; int r = b & 255;
        K = 256; N = 1024; n0 = (r & 31) * 32; k0 = (r >> 5) * 32;
        src = W1; dst = w1t;
    } else if (b < 5120) {              // W2 [4][1024][1024] -> same^T
        b -= 1024; s = b >> 10; int r = b & 1023;
        K = 1024; N = 1024; n0 = (r & 31) * 32; k0 = (r >> 5) * 32;
        src = W2; dst = w2t;
    } else {                            // W3 [4][1024][512] -> [4][512][1024]
        b -= 5120; s = b >> 9; int r = b & 511;
        K = 1024; N = 512; n0 = (r & 15) * 32; k0 = (r >> 4) * 32;
        src = W3; dst = w3t;
    }
    src += (size_t)s * K * N;
    dst += (size_t)s * N * K;
    const int tx = tid & 31, ty = tid >> 5;
#pragma unroll
    for (int j = 0; j < 32; j += 8)
        tile[ty + j][tx] = src[(size_t)(k0 + ty + j) * N + (n0 + tx)];
    __syncthreads();
#pragma unroll
    for (int j = 0; j < 32; j += 8)
        dst[(size_t)(n0 + ty + j) * K + (k0 + tx)] = f2bf(tile[tx][ty + j]);
}

// ---- fragment-load / MFMA-phase building blocks (compile-time H/V) ----
#define LDA(H)                                                                 \
    {                                                                          \
        _Pragma("unroll") for (int i = 0; i < 4; ++i)                          \
            _Pragma("unroll") for (int kk = 0; kk < 2; ++kk)                   \
                af[i][kk] = *(const bf16x8*)&buf[arow0 + ((H) << 12) +         \
                                                 (i << 10) + cs[kk]];          \
    }

#define LDB(V, BF)                                                             \
    {                                                                          \
        _Pragma("unroll") for (int j = 0; j < 2; ++j)                          \
            _Pragma("unroll") for (int kk = 0; kk < 2; ++kk)                   \
                BF[j][kk] = *(const bf16x8*)&buf[16384 + brow0 +               \
                                                 ((((V) << 1) + j) << 10) +    \
                                                 cs[kk]];                      \
    }

// barrier then pin: lgkmcnt(0) drains this wave's ds ops (race keystone),
// sched_barrier(0) stops MFMA hoisting above the pin (rule 18).
#define SYNC_PIN                                                               \
    __builtin_amdgcn_s_barrier();                                              \
    asm volatile("s_waitcnt lgkmcnt(0)" ::: "memory");                         \
    __builtin_amdgcn_sched_barrier(0);

#define MFMA16(H, V, BF)                                                       \
    {                                                                          \
        __builtin_amdgcn_s_setprio(1);                                         \
        _Pragma("unroll") for (int i = 0; i < 4; ++i)                          \
            _Pragma("unroll") for (int j = 0; j < 2; ++j)                      \
                _Pragma("unroll") for (int kk = 0; kk < 2; ++kk)               \
                    acc[((H) << 2) + i][((V) << 1) + j] =                      \
                        __builtin_amdgcn_mfma_f32_16x16x32_bf16(               \
                            af[i][kk], BF[j][kk],                              \
                            acc[((H) << 2) + i][((V) << 1) + j], 0, 0, 0);     \
        __builtin_amdgcn_s_setprio(0);                                         \
    }

// ------------- grouped GEMM: 256x256, BK=64, dbuf, 4-phase K-tile -------------
// C[m,n] = act(A[M,K] @ Wt[s][N,K]^T + bias[s][N]);  s = seps[agent(m)]
// 512 thr = 8 waves (2M x 4N); per-wave C = 128x64 (acc 8x4); 16x16x32 MFMA.
// LDS: 2 buffers x {A 256x64 | B 256x64} bf16 = 2 x 64KB. 128B rows,
// chunk ^ (l16&7) swizzle (0 conflicts, verified R10/R12).
template <int K, int N, bool RELU, bool OUT_BF16>
__global__ __launch_bounds__(512, 2) void gemm_mlp(
    const u16* __restrict__ Amat, const u16* __restrict__ Wt,
    const float* __restrict__ bias, const int* __restrict__ seps,
    void* __restrict__ outp) {
    constexpr int BK = 64;
    constexpr int NT = K / BK;
    constexpr int NNB = N / 256;               // n-blocks per m-stripe (4 or 2)
    constexpr int LNB = (NNB == 4) ? 2 : 1;
    extern __shared__ u16 lds[];               // 128 KB dynamic

    const int tid = threadIdx.x;
    const int wave = tid >> 6, lane = tid & 63;
    const int wm = wave >> 2, wn = wave & 3;
    const int quad = lane >> 4, l16 = lane & 15;

    // XCD swizzle: block i -> XCD i%8; all NNB n-blocks of one m-stripe are
    // dispatch-adjacent and share i%8 -> one XCD's L2 holds the A-stripe.
    const int bidx = blockIdx.x;
    const int t = bidx >> 3;
    const int mb = (t >> LNB) * 8 + (bidx & 7);
    const int nb = t & (NNB - 1);
    const int m0 = mb * 256, n0 = nb * 256;

    const int s = seps[m0 >> 12];              // 4096 rows per agent
    const u16* Ab = Amat + (size_t)m0 * K;
    const u16* Bb = Wt + ((size_t)s * N + n0) * K;

    // staging: half-tile (128 rows x 64 k) per STAGEH = 2 load16/thread.
    // Wave w, lane L: row = w*8 + (L>>3), LDS slot L&7 <- global chunk
    // (L&7)^(L>>3)  => LDS[r][c] = G[r][c ^ (r&7)]  (involution on read).
    const int srow = (wave << 3) + (lane >> 3);
    const int sch = ((lane & 7) ^ (lane >> 3)) << 3;
    const u16* gA = Ab + (size_t)srow * K + sch;
    const u16* gB = Bb + (size_t)srow * K + sch;
    const unsigned lsw = (unsigned)(wave << 9);   // wave*8 rows * 64 u16

    // ht: 0=A rows[0,128) 1=A rows[128,256) 2=B rows[0,128) 3=B rows[128,256)
    auto STAGEH = [&](int T1, int ht) {
        u16* dbuf = &lds[(T1 & 1) << 15];      // 32768 u16 per buffer
        const int k0 = T1 * BK;
        const u16* g = (ht & 2) ? gB : gA;
        const int r0 = (ht & 1) << 7;
#pragma unroll
        for (int q = 0; q < 2; ++q)
            load16(g + (size_t)(r0 + (q << 6)) * K + k0,
                   dbuf + ht * 8192 + (q << 12) + lsw);
    };

    // fragment read bases (u16 index): row stride 64 u16 = 128 B.
    // de-swizzle slot = chunk ^ (l16&7)  (row&7 == l16&7, rows step by 16).
    const int arow0 = ((wm << 7) + l16) << 6;
    const int brow0 = ((wn << 6) + l16) << 6;
    int cs[2];
    cs[0] = ((quad ^ (l16 & 7)) << 3);
    cs[1] = (((4 + quad) ^ (l16 & 7)) << 3);

    floatx4 acc[8][4];
#pragma unroll
    for (int i = 0; i < 8; ++i)
#pragma unroll
        for (int j = 0; j < 4; ++j) acc[i][j] = (floatx4){0.f, 0.f, 0.f, 0.f};

    // prologue: stage tile 0 fully, drain, publish.
    STAGEH(0, 0); STAGEH(0, 2); STAGEH(0, 3); STAGEH(0, 1);
    asm volatile("s_waitcnt vmcnt(0)" ::: "memory");
    __builtin_amdgcn_s_barrier();

    bf16x8 af[4][2], bf0[2][2], bf1[2][2];

#pragma unroll 1
    for (int T = 0; T < NT; ++T) {
        const u16* buf = &lds[(T & 1) << 15];
        const bool more = (T + 1 < NT);

        // ph0: reads (A0,B0) + stage A-lo,B-lo of T+1 | sync | MFMA(0,0)
        LDA(0); LDB(0, bf0);
        if (more) { STAGEH(T + 1, 0); STAGEH(T + 1, 2); }
        SYNC_PIN;
        MFMA16(0, 0, bf0);
        // ph1: reads (B1) + stage B-hi,A-hi of T+1 | sync | MFMA(0,1)
        LDB(1, bf1);
        if (more) { STAGEH(T + 1, 3); STAGEH(T + 1, 1); }
        SYNC_PIN;
        MFMA16(0, 1, bf1);
        // ph2: reads (A1) | sync | MFMA(1,1)
        LDA(1);
        SYNC_PIN;
        MFMA16(1, 1, bf1);
        // ph3: publish tile T+1 (vmcnt(0) ~3 windows after last issue),
        // then sync | MFMA(1,0)
        asm volatile("s_waitcnt vmcnt(0)" ::: "memory");
        SYNC_PIN;
        MFMA16(1, 0, bf0);
    }
    __syncthreads();   // all LDS traffic done before epilogue reuse

    // ---- epilogue: 8 mf-phases, LDS transpose, coalesced stores ----
    float* eps = (float*)lds;                  // [32][268] f32 per phase
    constexpr int EW = 268;
    float bv[4];
#pragma unroll
    for (int nf = 0; nf < 4; ++nf)
        bv[nf] = bias[s * N + n0 + (wn << 6) + (nf << 4) + l16];

    const int rL = tid & 63;                   // float4 column slot
    const int rw = tid >> 6;                   // row base

#pragma unroll
    for (int mf = 0; mf < 8; ++mf) {
#pragma unroll
        for (int nf = 0; nf < 4; ++nf)
#pragma unroll
            for (int r = 0; r < 4; ++r) {
                float v = acc[mf][nf][r] + bv[nf];
                if (RELU) v = fmaxf(v, 0.0f);
                eps[((wm << 4) + (quad << 2) + r) * EW + (wn << 6) + (nf << 4) + l16] = v;
            }
        __syncthreads();
#pragma unroll
        for (int j = 0; j < 4; ++j) {
            const int er = rw + (j << 3);      // 0..31
            const int grow = m0 + ((er >> 4) << 7) + (mf << 4) + (er & 15);
            const float4 v = *(const float4*)&eps[er * EW + (rL << 2)];
            if (OUT_BF16) {
                ushort4 o;
                o.x = f2bf(v.x); o.y = f2bf(v.y); o.z = f2bf(v.z); o.w = f2bf(v.w);
                *(ushort4*)((u16*)outp + (size_t)grow * N + n0 + (rL << 2)) = o;
            } else {
                *(float4*)((float*)outp + (size_t)grow * N + n0 + (rL << 2)) = v;
            }
        }
        __syncthreads();
    }
}

extern "C" void kernel_launch(void* const* d_in, const int* in_sizes, int n_in,
                              void* d_out, int out_size, void* d_ws, size_t ws_size,
                              hipStream_t stream) {
    const float* x  = (const float*)d_in[0];
    const float* W1 = (const float*)d_in[1];
    const float* b1 = (const float*)d_in[2];
    const float* W2 = (const float*)d_in[3];
    const float* b2 = (const float*)d_in[4];
    const float* W3 = (const float*)d_in[5];
    const float* b3 = (const float*)d_in[6];
    const int* seps = (const int*)d_in[7];

    char* ws = (char*)d_ws;
    u16* w1t = (u16*)(ws);                    //  2 MB: [4][1024][256]
    u16* w2t = (u16*)(ws + (2ull << 20));     //  8 MB: [4][1024][1024]
    u16* w3t = (u16*)(ws + (10ull << 20));    //  4 MB: [4][512][1024]
    u16* xb  = (u16*)(ws + (14ull << 20));    // 16 MB: [32768][256]
    u16* h1  = (u16*)(ws + (30ull << 20));    // 64 MB: [32768][1024]
    u16* h2  = (u16*)(ws + (94ull << 20));    // 64 MB: [32768][1024]

    // 128 KB dynamic LDS opt-in (host-side, once).
    static int attr_once = []() {
        auto k1 = gemm_mlp<256, 1024, true, true>;
        auto k2 = gemm_mlp<1024, 1024, true, true>;
        auto k3 = gemm_mlp<1024, 512, false, false>;
        hipFuncSetAttribute(reinterpret_cast<const void*>(k1),
                            hipFuncAttributeMaxDynamicSharedMemorySize, 131072);
        hipFuncSetAttribute(reinterpret_cast<const void*>(k2),
                            hipFuncAttributeMaxDynamicSharedMemorySize, 131072);
        hipFuncSetAttribute(reinterpret_cast<const void*>(k3),
                            hipFuncAttributeMaxDynamicSharedMemorySize, 131072);
        return 0;
    }();
    (void)attr_once;

    prep<<<15360, 256, 0, stream>>>(x, xb, W1, w1t, W2, w2t, W3, w3t);

    // L1: [32768,256]@[256,1024]^T +b1, relu -> h1 (bf16)
    gemm_mlp<256, 1024, true, true><<<512, 512, 131072, stream>>>(xb, w1t, b1, seps, h1);
    // L2: [32768,1024]@[1024,1024]^T +b2, relu -> h2 (bf16)
    gemm_mlp<1024, 1024, true, true><<<512, 512, 131072, stream>>>(h1, w2t, b2, seps, h2);
    // L3: [32768,1024]@[1024,512]^T +b3 -> out (f32)
    gemm_mlp<1024, 512, false, false><<<256, 512, 131072, stream>>>(h2, w3t, b3, seps, d_out);
}

// Round 6
// 250.203 us; speedup vs baseline: 1.1111x; 1.0136x over previous
//
#include <hip/hip_runtime.h>
#include <hip/hip_bf16.h>

// MultiAgentSEPSNetwork: A=8 agents, E=4096, O=256, H1=H2=1024, H3=512, S=4.
// M = A*E = 32768 rows. Only the seps_idx-selected net per agent is computed.
//
// R14: R13 (single barrier/phase + lgkm0 pin) = 73us L2, MfmaUtil 41%.
// Window audit: 1370 cyc/window vs 620 MFMA + ~880 read-drain -> the
// lgkmcnt(0) full drain at window start serializes drain+MFMA per wave.
// R11's failure was re-audited and was a STAGING INDEX BUG (8-chunk/row
// pattern in 4-chunk BK=32 rows), NOT a sync race -> relaxing the pin is
// not convicted. R14 = R13 with ONE change:
//   SYNC_PIN: {barrier; lgkmcnt(0); sched_barrier(0)}  ->
//             {sched_barrier(0); barrier}
// Fine-grained compiler lgkm waits let the first MFMA start after its own
// 2 frags land; the rest drain under the cluster. Hazard audit: every
// fragment read is consumed by an MFMA in its own window; SB0-before-
// barrier pins consumption above the barrier; DMA overwrite of any read's
// source region is >=1 barrier after that consumption -> WAR safe.
// Kept (verified): 256x256, BK=64, dbuf 2x64KB, quadrant phases, staging
// 4+4 at ph0/ph1 windows, vmcnt(0) publish before ph3 barrier, zero-
// conflict chunk^(l16&7) swizzle, XCD grid swizzle, setprio clusters,
// LDS-transpose epilogue.

typedef unsigned short u16;
typedef __bf16 bf16x8 __attribute__((ext_vector_type(8)));
typedef float floatx4 __attribute__((ext_vector_type(4)));

__device__ __forceinline__ u16 f2bf(float f) {
    union { float f; unsigned int u; } v; v.f = f;
    unsigned int u = v.u;
    return (u16)((u + 0x7FFFu + ((u >> 16) & 1u)) >> 16);
}

// global -> LDS direct DMA, 16 B/lane. LDS dest = wave-uniform base + lane*16.
__device__ __forceinline__ void load16(const void* g, void* l) {
    __builtin_amdgcn_global_load_lds(
        (const __attribute__((address_space(1))) void*)(unsigned long long)g,
        (__attribute__((address_space(3))) void*)(unsigned int)(unsigned long long)l,
        16, 0, 0);
}

// ---------------- fused prep: x->bf16 + 3 weight transposes ----------------
__global__ __launch_bounds__(256) void prep(
    const float* __restrict__ x, u16* __restrict__ xb,
    const float* __restrict__ W1, u16* __restrict__ w1t,
    const float* __restrict__ W2, u16* __restrict__ w2t,
    const float* __restrict__ W3, u16* __restrict__ w3t) {
    __shared__ float tile[32][33];
    int b = blockIdx.x;
    const int tid = threadIdx.x;
    if (b < 8192) {
        int i = (b * 256 + tid) * 4;
        float4 v = *(const float4*)(x + i);
        ushort4 o;
        o.x = f2bf(v.x); o.y = f2bf(v.y); o.z = f2bf(v.z); o.w = f2bf(v.w);
        *(ushort4*)(xb + i) = o;
        return;
    }
    b -= 8192;
    const float* src; u16* dst; int K, N, n0, k0, s;
    if (b < 1024) {                     // W1 [4][256][1024] -> [4][1024][256]
        s = b >> 8; int r = b & 255;
        K = 256; N = 1024; n0 = (r & 31) * 32; k0 = (r >> 5) * 32;
        src = W1; dst = w1t;
    } else if (b < 5120) {              // W2 [4][1024][1024] -> same^T
        b -= 1024; s = b >> 10; int r = b & 1023;
        K = 1024; N = 1024; n0 = (r & 31) * 32; k0 = (r >> 5) * 32;
        src = W2; dst = w2t;
    } else {                            // W3 [4][1024][512] -> [4][512][1024]
        b -= 5120; s = b >> 9; int r = b & 511;
        K = 1024; N = 512; n0 = (r & 15) * 32; k0 = (r >> 4) * 32;
        src = W3; dst = w3t;
    }
    src += (size_t)s * K * N;
    dst += (size_t)s * N * K;
    const int tx = tid & 31, ty = tid >> 5;
#pragma unroll
    for (int j = 0; j < 32; j += 8)
        tile[ty + j][tx] = src[(size_t)(k0 + ty + j) * N + (n0 + tx)];
    __syncthreads();
#pragma unroll
    for (int j = 0; j < 32; j += 8)
        dst[(size_t)(n0 + ty + j) * K + (k0 + tx)] = f2bf(tile[tx][ty + j]);
}

// ---- fragment-load / MFMA-phase building blocks (compile-time H/V) ----
#define LDA(H)                                                                 \
    {                                                                          \
        _Pragma("unroll") for (int i = 0; i < 4; ++i)                          \
            _Pragma("unroll") for (int kk = 0; kk < 2; ++kk)                   \
                af[i][kk] = *(const bf16x8*)&buf[arow0 + ((H) << 12) +         \
                                                 (i << 10) + cs[kk]];          \
    }

#define LDB(V, BF)                                                             \
    {                                                                          \
        _Pragma("unroll") for (int j = 0; j < 2; ++j)                          \
            _Pragma("unroll") for (int kk = 0; kk < 2; ++kk)                   \
                BF[j][kk] = *(const bf16x8*)&buf[16384 + brow0 +               \
                                                 ((((V) << 1) + j) << 10) +    \
                                                 cs[kk]];                      \
    }

// R14 sync: sched_barrier(0) BEFORE the barrier pins each window's MFMA
// consumption above it (no sinking past the barrier -> reads drained by
// consumption before the wave crosses). NO lgkmcnt(0) drain: compiler
// emits fine-grained per-frag lgkm waits, so MFMAs overlap the tail of
// the read drain instead of waiting for all of it.
#define SYNC_PIN                                                               \
    __builtin_amdgcn_sched_barrier(0);                                         \
    __builtin_amdgcn_s_barrier();

#define MFMA16(H, V, BF)                                                       \
    {                                                                          \
        __builtin_amdgcn_s_setprio(1);                                         \
        _Pragma("unroll") for (int i = 0; i < 4; ++i)                          \
            _Pragma("unroll") for (int j = 0; j < 2; ++j)                      \
                _Pragma("unroll") for (int kk = 0; kk < 2; ++kk)               \
                    acc[((H) << 2) + i][((V) << 1) + j] =                      \
                        __builtin_amdgcn_mfma_f32_16x16x32_bf16(               \
                            af[i][kk], BF[j][kk],                              \
                            acc[((H) << 2) + i][((V) << 1) + j], 0, 0, 0);     \
        __builtin_amdgcn_s_setprio(0);                                         \
    }

// ------------- grouped GEMM: 256x256, BK=64, dbuf, 4-phase K-tile -------------
// C[m,n] = act(A[M,K] @ Wt[s][N,K]^T + bias[s][N]);  s = seps[agent(m)]
// 512 thr = 8 waves (2M x 4N); per-wave C = 128x64 (acc 8x4); 16x16x32 MFMA.
// LDS: 2 buffers x {A 256x64 | B 256x64} bf16 = 2 x 64KB. 128B rows,
// chunk ^ (l16&7) swizzle (0 conflicts, verified R10/R12/R13).
template <int K, int N, bool RELU, bool OUT_BF16>
__global__ __launch_bounds__(512, 2) void gemm_mlp(
    const u16* __restrict__ Amat, const u16* __restrict__ Wt,
    const float* __restrict__ bias, const int* __restrict__ seps,
    void* __restrict__ outp) {
    constexpr int BK = 64;
    constexpr int NT = K / BK;
    constexpr int NNB = N / 256;               // n-blocks per m-stripe (4 or 2)
    constexpr int LNB = (NNB == 4) ? 2 : 1;
    extern __shared__ u16 lds[];               // 128 KB dynamic

    const int tid = threadIdx.x;
    const int wave = tid >> 6, lane = tid & 63;
    const int wm = wave >> 2, wn = wave & 3;
    const int quad = lane >> 4, l16 = lane & 15;

    // XCD swizzle: block i -> XCD i%8; all NNB n-blocks of one m-stripe are
    // dispatch-adjacent and share i%8 -> one XCD's L2 holds the A-stripe.
    const int bidx = blockIdx.x;
    const int t = bidx >> 3;
    const int mb = (t >> LNB) * 8 + (bidx & 7);
    const int nb = t & (NNB - 1);
    const int m0 = mb * 256, n0 = nb * 256;

    const int s = seps[m0 >> 12];              // 4096 rows per agent
    const u16* Ab = Amat + (size_t)m0 * K;
    const u16* Bb = Wt + ((size_t)s * N + n0) * K;

    // staging: half-tile (128 rows x 64 k) per STAGEH = 2 load16/thread.
    // Wave w, lane L: row = w*8 + (L>>3), LDS slot L&7 <- global chunk
    // (L&7)^(L>>3)  => LDS[r][c] = G[r][c ^ (r&7)]  (involution on read).
    const int srow = (wave << 3) + (lane >> 3);
    const int sch = ((lane & 7) ^ (lane >> 3)) << 3;
    const u16* gA = Ab + (size_t)srow * K + sch;
    const u16* gB = Bb + (size_t)srow * K + sch;
    const unsigned lsw = (unsigned)(wave << 9);   // wave*8 rows * 64 u16

    // ht: 0=A rows[0,128) 1=A rows[128,256) 2=B rows[0,128) 3=B rows[128,256)
    auto STAGEH = [&](int T1, int ht) {
        u16* dbuf = &lds[(T1 & 1) << 15];      // 32768 u16 per buffer
        const int k0 = T1 * BK;
        const u16* g = (ht & 2) ? gB : gA;
        const int r0 = (ht & 1) << 7;
#pragma unroll
        for (int q = 0; q < 2; ++q)
            load16(g + (size_t)(r0 + (q << 6)) * K + k0,
                   dbuf + ht * 8192 + (q << 12) + lsw);
    };

    // fragment read bases (u16 index): row stride 64 u16 = 128 B.
    // de-swizzle slot = chunk ^ (l16&7)  (row&7 == l16&7, rows step by 16).
    const int arow0 = ((wm << 7) + l16) << 6;
    const int brow0 = ((wn << 6) + l16) << 6;
    int cs[2];
    cs[0] = ((quad ^ (l16 & 7)) << 3);
    cs[1] = (((4 + quad) ^ (l16 & 7)) << 3);

    floatx4 acc[8][4];
#pragma unroll
    for (int i = 0; i < 8; ++i)
#pragma unroll
        for (int j = 0; j < 4; ++j) acc[i][j] = (floatx4){0.f, 0.f, 0.f, 0.f};

    // prologue: stage tile 0 fully, drain, publish.
    STAGEH(0, 0); STAGEH(0, 2); STAGEH(0, 3); STAGEH(0, 1);
    asm volatile("s_waitcnt vmcnt(0)" ::: "memory");
    __builtin_amdgcn_s_barrier();

    bf16x8 af[4][2], bf0[2][2], bf1[2][2];

#pragma unroll 1
    for (int T = 0; T < NT; ++T) {
        const u16* buf = &lds[(T & 1) << 15];
        const bool more = (T + 1 < NT);

        // ph0: reads (A0,B0) + stage A-lo,B-lo of T+1 | sync | MFMA(0,0)
        LDA(0); LDB(0, bf0);
        if (more) { STAGEH(T + 1, 0); STAGEH(T + 1, 2); }
        SYNC_PIN;
        MFMA16(0, 0, bf0);
        // ph1: reads (B1) + stage B-hi,A-hi of T+1 | sync | MFMA(0,1)
        LDB(1, bf1);
        if (more) { STAGEH(T + 1, 3); STAGEH(T + 1, 1); }
        SYNC_PIN;
        MFMA16(0, 1, bf1);
        // ph2: reads (A1) | sync | MFMA(1,1)
        LDA(1);
        SYNC_PIN;
        MFMA16(1, 1, bf1);
        // ph3: publish tile T+1 (vmcnt(0) ~3 windows after last issue),
        // then sync | MFMA(1,0)
        asm volatile("s_waitcnt vmcnt(0)" ::: "memory");
        SYNC_PIN;
        MFMA16(1, 0, bf0);
    }
    __syncthreads();   // all LDS traffic done before epilogue reuse

    // ---- epilogue: 8 mf-phases, LDS transpose, coalesced stores ----
    float* eps = (float*)lds;                  // [32][268] f32 per phase
    constexpr int EW = 268;
    float bv[4];
#pragma unroll
    for (int nf = 0; nf < 4; ++nf)
        bv[nf] = bias[s * N + n0 + (wn << 6) + (nf << 4) + l16];

    const int rL = tid & 63;                   // float4 column slot
    const int rw = tid >> 6;                   // row base

#pragma unroll
    for (int mf = 0; mf < 8; ++mf) {
#pragma unroll
        for (int nf = 0; nf < 4; ++nf)
#pragma unroll
            for (int r = 0; r < 4; ++r) {
                float v = acc[mf][nf][r] + bv[nf];
                if (RELU) v = fmaxf(v, 0.0f);
                eps[((wm << 4) + (quad << 2) + r) * EW + (wn << 6) + (nf << 4) + l16] = v;
            }
        __syncthreads();
#pragma unroll
        for (int j = 0; j < 4; ++j) {
            const int er = rw + (j << 3);      // 0..31
            const int grow = m0 + ((er >> 4) << 7) + (mf << 4) + (er & 15);
            const float4 v = *(const float4*)&eps[er * EW + (rL << 2)];
            if (OUT_BF16) {
                ushort4 o;
                o.x = f2bf(v.x); o.y = f2bf(v.y); o.z = f2bf(v.z); o.w = f2bf(v.w);
                *(ushort4*)((u16*)outp + (size_t)grow * N + n0 + (rL << 2)) = o;
            } else {
                *(float4*)((float*)outp + (size_t)grow * N + n0 + (rL << 2)) = v;
            }
        }
        __syncthreads();
    }
}

extern "C" void kernel_launch(void* const* d_in, const int* in_sizes, int n_in,
                              void* d_out, int out_size, void* d_ws, size_t ws_size,
                              hipStream_t stream) {
    const float* x  = (const float*)d_in[0];
    const float* W1 = (const float*)d_in[1];
    const float* b1 = (const float*)d_in[2];
    const float* W2 = (const float*)d_in[3];
    const float* b2 = (const float*)d_in[4];
    const float* W3 = (const float*)d_in[5];
    const float* b3 = (const float*)d_in[6];
    const int* seps = (const int*)d_in[7];

    char* ws = (char*)d_ws;
    u16* w1t = (u16*)(ws);                    //  2 MB: [4][1024][256]
    u16* w2t = (u16*)(ws + (2ull << 20));     //  8 MB: [4][1024][1024]
    u16* w3t = (u16*)(ws + (10ull << 20));    //  4 MB: [4][512][1024]
    u16* xb  = (u16*)(ws + (14ull << 20));    // 16 MB: [32768][256]
    u16* h1  = (u16*)(ws + (30ull << 20));    // 64 MB: [32768][1024]
    u16* h2  = (u16*)(ws + (94ull << 20));    // 64 MB: [32768][1024]

    // 128 KB dynamic LDS opt-in (host-side, once).
    static int attr_once = []() {
        auto k1 = gemm_mlp<256, 1024, true, true>;
        auto k2 = gemm_mlp<1024, 1024, true, true>;
        auto k3 = gemm_mlp<1024, 512, false, false>;
        hipFuncSetAttribute(reinterpret_cast<const void*>(k1),
                            hipFuncAttributeMaxDynamicSharedMemorySize, 131072);
        hipFuncSetAttribute(reinterpret_cast<const void*>(k2),
                            hipFuncAttributeMaxDynamicSharedMemorySize, 131072);
        hipFuncSetAttribute(reinterpret_cast<const void*>(k3),
                            hipFuncAttributeMaxDynamicSharedMemorySize, 131072);
        return 0;
    }();
    (void)attr_once;

    prep<<<15360, 256, 0, stream>>>(x, xb, W1, w1t, W2, w2t, W3, w3t);

    // L1: [32768,256]@[256,1024]^T +b1, relu -> h1 (bf16)
    gemm_mlp<256, 1024, true, true><<<512, 512, 131072, stream>>>(xb, w1t, b1, seps, h1);
    // L2: [32768,1024]@[1024,1024]^T +b2, relu -> h2 (bf16)
    gemm_mlp<1024, 1024, true, true><<<512, 512, 131072, stream>>>(h1, w2t, b2, seps, h2);
    // L3: [32768,1024]@[1024,512]^T +b3 -> out (f32)
    gemm_mlp<1024, 512, false, false><<<256, 512, 131072, stream>>>(h2, w3t, b3, seps, d_out);
}